// Round 8
// baseline (307.776 us; speedup 1.0000x reference)
//
#include <hip/hip_runtime.h>
#include <hip/hip_bf16.h>

// GCN layer: out = (D^-1/2 A D^-1/2 X) W^T + b
// Round 8: ONE persistent kernel (plain launch; cooperative launch proved
// non-functional in this harness in R7). Software global barrier, safe by
// capacity: grid=256 blocks (1 per CU guaranteed at 1024 thr / <64KB LDS /
// VGPR<=128) + bounded spins. Poison-agnostic init handshake.
// Phases: A zero cnt | B cast+fill | C dis/degc | D gather+MFMA (ticket).
//
// ws: sync[16] | cnt[N*16] 3.2MB | ell[N*64 u16] 6.4MB | dis[N] | degc[N] |
//     xb[N*128 bf16] 12.8MB | wb[128*128 bf16]  ~= 22.7 MB

typedef short v8s __attribute__((ext_vector_type(8)));
typedef float v4f __attribute__((ext_vector_type(4)));

#define ELLCAP 64      // deg ~ Poisson(16); P(deg>64) ~ 1e-19/node. Guarded.
#define CSTRIDE 16     // one counter per 64 B line (R6-verified)
#define GRID 256       // = #CUs -> co-residency by capacity
#define BLK 1024       // 16 waves/block
#define ROWSTRIDE 136  // 128 bf16 + 8 pad shorts; 272 B rows (16B-aligned)
#define TILEROWS 128
#define MAGICF 0x51CA7B3Du

static __device__ __forceinline__ unsigned int f2bf(float f) {
    __hip_bfloat16 h = __float2bfloat16(f);  // RNE
    return (unsigned int)__builtin_bit_cast(unsigned short, h);
}

// Grid barrier: monotonic counter, device-scope atomics, bounded spin.
static __device__ __forceinline__ void grid_bar(unsigned* bar, unsigned target) {
    __syncthreads();
    if (threadIdx.x == 0) {
        __threadfence();  // publish this block's (XCD's) writes device-wide
        __hip_atomic_fetch_add(bar, 1u, __ATOMIC_ACQ_REL,
                               __HIP_MEMORY_SCOPE_AGENT);
        unsigned spins = 0;
        while (__hip_atomic_load(bar, __ATOMIC_ACQUIRE,
                                 __HIP_MEMORY_SCOPE_AGENT) < target) {
            __builtin_amdgcn_s_sleep(2);
            if (++spins > 20000000u) break;  // bail: wrong answer > hang
        }
        __threadfence();
    }
    __syncthreads();
}

__global__ __launch_bounds__(BLK, 4) void k_all(
    const int* __restrict__ idx, unsigned* sync_, int* cnt,
    unsigned short* ell, float* dis, unsigned char* degc,
    const float4* __restrict__ x4, const float4* __restrict__ w4,
    ushort4* xb4, ushort4* wb4, const float* __restrict__ bias,
    float* __restrict__ out, int N, int E, int ntiles) {
    const int tid = threadIdx.x;
    const int bid = blockIdx.x;
    const int g = bid * BLK + tid;

    // ---- init handshake (works for any initial ws contents != MAGIC) ----
    if (tid == 0) {
        if (bid == 0) {
            sync_[0] = 0u;  // barrier counter
            sync_[1] = 0u;  // phase-D ticket
            __threadfence();
            __hip_atomic_store(&sync_[2], MAGICF, __ATOMIC_RELEASE,
                               __HIP_MEMORY_SCOPE_AGENT);
        } else {
            unsigned spins = 0;
            while (__hip_atomic_load(&sync_[2], __ATOMIC_ACQUIRE,
                                     __HIP_MEMORY_SCOPE_AGENT) != MAGICF) {
                __builtin_amdgcn_s_sleep(2);
                if (++spins > 20000000u) break;
            }
        }
    }
    __syncthreads();

    // ---- phase A: zero spread counters ----
    {
        uint4* cnt4 = (uint4*)cnt;
        int z4 = N * (CSTRIDE / 4);
        uint4 zz = make_uint4(0, 0, 0, 0);
        for (int i = g; i < z4; i += GRID * BLK) cnt4[i] = zz;
    }
    grid_bar(&sync_[0], GRID);

    // ---- phase B: interleaved bf16 cast + ELL fill (R6-verified mapping,
    //      virtual 256-thread blocks; fill = 4 independent atomics/thread) ----
    {
        const int nx4 = N * 32, nw4 = 4096;
        const int C = (nx4 + nw4 + 255) / 256;
        const int F = (E + 1023) / 1024;
        int S = (C + F) / F;
        if (S < 2) S = 2;
        const int T = C + F;
        const int vb0 = bid * 4 + (tid >> 8);
        const int vtid = tid & 255;
        for (int u = vb0; u < T; u += GRID * 4) {
            int q = u / S;
            bool isFill = ((u % S) == (S - 1)) && (q < F);
            if (isFill) {
                int e0 = (q * 256 + vtid) * 4;
                if (e0 + 3 < E) {
                    int4 r4 = *(const int4*)&idx[e0];
                    int4 c4 = *(const int4*)&idx[E + e0];
                    int p0 = atomicAdd(&cnt[(size_t)r4.x * CSTRIDE], 1);
                    int p1 = atomicAdd(&cnt[(size_t)r4.y * CSTRIDE], 1);
                    int p2 = atomicAdd(&cnt[(size_t)r4.z * CSTRIDE], 1);
                    int p3 = atomicAdd(&cnt[(size_t)r4.w * CSTRIDE], 1);
                    if (p0 < ELLCAP) ell[(size_t)r4.x * ELLCAP + p0] = (unsigned short)c4.x;
                    if (p1 < ELLCAP) ell[(size_t)r4.y * ELLCAP + p1] = (unsigned short)c4.y;
                    if (p2 < ELLCAP) ell[(size_t)r4.z * ELLCAP + p2] = (unsigned short)c4.z;
                    if (p3 < ELLCAP) ell[(size_t)r4.w * ELLCAP + p3] = (unsigned short)c4.w;
                } else {
                    for (int k = 0; k < 4; ++k) {
                        int e = e0 + k;
                        if (e < E) {
                            int row = idx[e], col = idx[E + e];
                            int p = atomicAdd(&cnt[(size_t)row * CSTRIDE], 1);
                            if (p < ELLCAP)
                                ell[(size_t)row * ELLCAP + p] = (unsigned short)col;
                        }
                    }
                }
            } else {
                int cb = u - ((q < F) ? (q + (((u % S) == (S - 1)) ? 1 : 0)) : F);
                int i = cb * 256 + vtid;
                const float4* s;
                ushort4* d;
                int j;
                if (i < nx4) { s = x4; d = xb4; j = i; }
                else if (i < nx4 + nw4) { s = w4; d = wb4; j = i - nx4; }
                else continue;
                float4 v = s[j];
                ushort4 o;
                o.x = (unsigned short)f2bf(v.x);
                o.y = (unsigned short)f2bf(v.y);
                o.z = (unsigned short)f2bf(v.z);
                o.w = (unsigned short)f2bf(v.w);
                d[j] = o;
            }
        }
    }
    grid_bar(&sync_[0], 2u * GRID);

    // ---- phase C: compact dis (f32, 200KB hot) + deg (u8) ----
    for (int n = g; n < N; n += GRID * BLK) {
        int d = cnt[(size_t)n * CSTRIDE];
        dis[n] = (d > 0) ? rsqrtf((float)d) : 0.0f;
        degc[n] = (unsigned char)(d > ELLCAP ? ELLCAP : d);
    }
    grid_bar(&sync_[0], 3u * GRID);

    // ---- phase D: gather + MFMA over 128-row tiles (dynamic ticket) ----
    __shared__ __align__(16) unsigned short smem[TILEROWS * ROWSTRIDE];
    __shared__ int s_tile;
    const unsigned int* xb32 = (const unsigned int*)xb4;
    const v8s* Wb8 = (const v8s*)wb4;
    const int wv = tid >> 6, lane = tid & 63;
    for (;;) {
        if (tid == 0)
            s_tile = (int)__hip_atomic_fetch_add(&sync_[1], 1u, __ATOMIC_RELAXED,
                                                 __HIP_MEMORY_SCOPE_AGENT);
        __syncthreads();
        int t = s_tile;
        if (t >= ntiles) break;
        int nb0 = t * TILEROWS;

        // gather: wave wv owns rows wv*8 .. wv*8+7 (R6-verified inner loop)
        for (int i = 0; i < 8; ++i) {
            int lrow = wv * 8 + i;
            int n = nb0 + lrow;
            float acc0 = 0.f, acc1 = 0.f;
            if (n < N) {
                int d = degc[n];
                int c = 0;
                float wgt = 0.f;
                if (lane < d) {
                    c = ell[(size_t)n * ELLCAP + lane];
                    wgt = dis[c];
                }
                int wbits = __builtin_bit_cast(int, wgt);
                for (int j = 0; j < d; j += 8) {
                    int cc[8];
                    float ww[8];
#pragma unroll
                    for (int u = 0; u < 8; ++u) {
                        cc[u] = __builtin_amdgcn_readlane(c, j + u);
                        ww[u] = __builtin_bit_cast(
                            float, __builtin_amdgcn_readlane(wbits, j + u));
                    }
                    unsigned uu[8];
#pragma unroll
                    for (int u = 0; u < 8; ++u)
                        uu[u] = xb32[(size_t)cc[u] * 64 + lane];
#pragma unroll
                    for (int u = 0; u < 8; ++u) {
                        acc0 += ww[u] * __builtin_bit_cast(float, uu[u] << 16);
                        acc1 += ww[u] * __builtin_bit_cast(float, uu[u] & 0xFFFF0000u);
                    }
                }
                float sc = dis[n];
                acc0 *= sc;
                acc1 *= sc;
            }
            unsigned pack = f2bf(acc0) | (f2bf(acc1) << 16);
            *(unsigned int*)&smem[(size_t)lrow * ROWSTRIDE + lane * 2] = pack;
        }
        __syncthreads();

        // MFMA (R6-verified layout). 16 waves cover 4 sub-tiles of 32 rows:
        // sub-tile st=wv>>2; within: row-half (wv&1), col-half ((wv&3)>>1).
        {
            int st = wv >> 2, w2 = wv & 3;
            int quad = lane >> 4, m16 = lane & 15;
            int lrow = st * 32 + (w2 & 1) * 16 + m16;
            v8s afrag[4];
#pragma unroll
            for (int kk = 0; kk < 4; ++kk)
                afrag[kk] = *(const v8s*)&smem[lrow * ROWSTRIDE + kk * 32 + quad * 8];
            int rbase = nb0 + st * 32 + (w2 & 1) * 16 + quad * 4;
            int jbase = (w2 >> 1) * 64;
#pragma unroll
            for (int jt = 0; jt < 4; ++jt) {
                int jcol = jbase + jt * 16 + m16;
                v4f acc = {0.f, 0.f, 0.f, 0.f};
#pragma unroll
                for (int kk = 0; kk < 4; ++kk) {
                    v8s bfrag = Wb8[jcol * 16 + kk * 4 + quad];
                    acc = __builtin_amdgcn_mfma_f32_16x16x32_bf16(afrag[kk], bfrag,
                                                                  acc, 0, 0, 0);
                }
                float bj = bias[jcol];
#pragma unroll
                for (int r = 0; r < 4; ++r) {
                    int row = rbase + r;
                    if (row < N) out[(size_t)row * 128 + jcol] = acc[r] + bj;
                }
            }
        }
        __syncthreads();  // protect smem before next tile's gather
    }
}

extern "C" void kernel_launch(void* const* d_in, const int* in_sizes, int n_in,
                              void* d_out, int out_size, void* d_ws, size_t ws_size,
                              hipStream_t stream) {
    const float* x = (const float*)d_in[0];
    const int* idx = (const int*)d_in[1];
    const float* W = (const float*)d_in[2];
    const float* b = (const float*)d_in[3];
    float* out = (float*)d_out;

    int N = in_sizes[0] / 128;  // 50000
    int E = in_sizes[1] / 2;    // 800000
    int ntiles = (N + TILEROWS - 1) / TILEROWS;  // 391

    char* p = (char*)d_ws;
    auto alloc = [&](size_t bytes) {
        char* r = p;
        p += (bytes + 63) & ~(size_t)63;
        return r;
    };
    unsigned* sync_ = (unsigned*)alloc(64);
    int* cnt = (int*)alloc((size_t)N * CSTRIDE * 4);                       // 3.2 MB
    unsigned short* ell = (unsigned short*)alloc((size_t)N * ELLCAP * 2);  // 6.4 MB
    float* dis = (float*)alloc((size_t)N * 4);
    unsigned char* degc = (unsigned char*)alloc((size_t)N);
    ushort4* xb = (ushort4*)alloc((size_t)N * 128 * 2);  // 12.8 MB
    ushort4* wb = (ushort4*)alloc(128 * 128 * 2);        // 32 KB

    hipLaunchKernelGGL(k_all, dim3(GRID), dim3(BLK), 0, stream, idx, sync_, cnt,
                       ell, dis, degc, (const float4*)x, (const float4*)W, xb, wb,
                       b, out, N, E, ntiles);
}

// Round 9
// 208.379 us; speedup vs baseline: 1.4770x; 1.4770x over previous
//
#include <hip/hip_runtime.h>
#include <hip/hip_bf16.h>

// GCN layer: out = (D^-1/2 A D^-1/2 X) W^T + b
// Round 9: back to multi-dispatch (R8 proved the total-vs-kernel gap is FIXED
// harness overhead ~60-75us, not per-dispatch; persistent kernel regressed).
//   memset cnt | k_fill (ELL, 4 edges/thr) | k_prep (dis + degc + xs=dis*x in
//   bf16 + zero pad row + W cast) | k_fused (weight-free gather + MFMA).
// Gather uses pre-scaled xs: pad slots -> zero row N; inner loop = load+2 adds.
//
// ws: cnt[N*16] 3.2MB | ell[N*64 u16] 6.4MB | dis[N] | degc[N] |
//     xs[(nrb*256)*128 bf16] 12.85MB | wb 32KB  ~= 22.7 MB (<= 26 MB proven)

typedef short v8s __attribute__((ext_vector_type(8)));
typedef float v4f __attribute__((ext_vector_type(4)));

#define ELLCAP 64      // deg ~ Poisson(16); P(deg>64) ~ 1e-19/node. Guarded.
#define CSTRIDE 16     // one counter per 64 B line (R6-verified atomic fix)
#define ROWSTRIDE 136  // 128 bf16 + 8 pad shorts; 272 B rows (16B-aligned)

static __device__ __forceinline__ unsigned int f2bf(float f) {
    __hip_bfloat16 h = __float2bfloat16(f);  // RNE
    return (unsigned int)__builtin_bit_cast(unsigned short, h);
}

// ELL build: 4 edges/thread (int4 loads, 4 independent atomic chains).
__global__ __launch_bounds__(256) void k_fill(const int* __restrict__ idx,
                                              int* __restrict__ cnt,
                                              unsigned short* __restrict__ ell,
                                              int E) {
    int e0 = (blockIdx.x * 256 + threadIdx.x) * 4;
    if (e0 >= E) return;
    if (e0 + 3 < E) {
        int4 r4 = *(const int4*)&idx[e0];
        int4 c4 = *(const int4*)&idx[E + e0];
        int p0 = atomicAdd(&cnt[(size_t)r4.x * CSTRIDE], 1);
        int p1 = atomicAdd(&cnt[(size_t)r4.y * CSTRIDE], 1);
        int p2 = atomicAdd(&cnt[(size_t)r4.z * CSTRIDE], 1);
        int p3 = atomicAdd(&cnt[(size_t)r4.w * CSTRIDE], 1);
        if (p0 < ELLCAP) ell[(size_t)r4.x * ELLCAP + p0] = (unsigned short)c4.x;
        if (p1 < ELLCAP) ell[(size_t)r4.y * ELLCAP + p1] = (unsigned short)c4.y;
        if (p2 < ELLCAP) ell[(size_t)r4.z * ELLCAP + p2] = (unsigned short)c4.z;
        if (p3 < ELLCAP) ell[(size_t)r4.w * ELLCAP + p3] = (unsigned short)c4.w;
    } else {
        for (int k = 0; k < 4; ++k) {
            int e = e0 + k;
            if (e < E) {
                int row = idx[e], col = idx[E + e];
                int p = atomicAdd(&cnt[(size_t)row * CSTRIDE], 1);
                if (p < ELLCAP) ell[(size_t)row * ELLCAP + p] = (unsigned short)col;
            }
        }
    }
}

// Prep: per 256-row block -> dis (f32), degc (u8), xs = bf16(dis[r] * x[r])
// straight from f32 x. Rows >= N (incl. pad row N) are written as zeros.
// Blocks >= nrb cast W (f32 -> bf16).
__global__ __launch_bounds__(256) void k_prep(
    const int* __restrict__ cnt, const float2* __restrict__ x2,
    const float4* __restrict__ w4, float* __restrict__ dis,
    unsigned char* __restrict__ degc, unsigned int* __restrict__ xs32,
    ushort4* __restrict__ wb4, int N, int nrb) {
    int b = blockIdx.x, t = threadIdx.x;
    if (b >= nrb) {  // W cast: 16 blocks x 256 thr = 4096 float4s
        int i = (b - nrb) * 256 + t;
        float4 v = w4[i];
        ushort4 o;
        o.x = (unsigned short)f2bf(v.x);
        o.y = (unsigned short)f2bf(v.y);
        o.z = (unsigned short)f2bf(v.z);
        o.w = (unsigned short)f2bf(v.w);
        wb4[i] = o;
        return;
    }
    __shared__ float sdis[256];
    int r = b * 256 + t;
    float s = 0.f;
    if (r < N) {
        int d = cnt[(size_t)r * CSTRIDE];
        s = (d > 0) ? rsqrtf((float)d) : 0.0f;
        dis[r] = s;
        degc[r] = (unsigned char)(d > ELLCAP ? ELLCAP : d);
    }
    sdis[t] = s;
    __syncthreads();
    // scale this block's 256 rows: 16384 dwords, coalesced float2 loads
    size_t base = (size_t)b * 16384;
    for (int k = 0; k < 64; ++k) {
        int i = k * 256 + t;
        int lr = i >> 6;  // local row
        unsigned outv = 0u;
        if (b * 256 + lr < N) {
            float2 v = x2[base + i];
            float ss = sdis[lr];
            outv = f2bf(v.x * ss) | (f2bf(v.y * ss) << 16);
        }
        xs32[base + i] = outv;  // rows >= N (incl. pad row N) -> zeros
    }
}

// Fused gather + GEMM. Block = 256 threads = 4 waves, 32 output rows.
// Gather: one wave/node, lane owns 2 channels (1 dword of xs). Pad slots
// (lane >= deg) select col = N -> zero row -> contribute nothing. Inner loop:
// 16 readlanes + 16 loads in flight + 32 adds per 16 edges. No weights.
__global__ __launch_bounds__(256) void k_fused(
    const unsigned short* __restrict__ ell, const unsigned char* __restrict__ degc,
    const float* __restrict__ dis, const unsigned int* __restrict__ xs32,
    const v8s* __restrict__ Wb8, const float* __restrict__ bias,
    float* __restrict__ out, int N) {
    __shared__ __align__(16) unsigned short smem[32 * ROWSTRIDE];
    const int nb0 = blockIdx.x * 32;
    const int wv = threadIdx.x >> 6, lane = threadIdx.x & 63;

    for (int i = 0; i < 8; ++i) {
        int lrow = wv * 8 + i;
        int n = nb0 + lrow;
        float acc0 = 0.f, acc1 = 0.f;
        if (n < N) {
            int d = degc[n];
            int cl = ell[(size_t)n * ELLCAP + lane];  // stale slots never used
            int c = (lane < d) ? cl : N;              // pad -> zero row
            for (int j = 0; j < d; j += 16) {         // j in {0,16,32,48}
                int cc[16];
#pragma unroll
                for (int u = 0; u < 16; ++u)
                    cc[u] = __builtin_amdgcn_readlane(c, j + u);  // idx <= 63
                unsigned uu[16];
#pragma unroll
                for (int u = 0; u < 16; ++u)
                    uu[u] = xs32[(size_t)cc[u] * 64 + lane];
#pragma unroll
                for (int u = 0; u < 16; ++u) {
                    acc0 += __builtin_bit_cast(float, uu[u] << 16);
                    acc1 += __builtin_bit_cast(float, uu[u] & 0xFFFF0000u);
                }
            }
            float s = dis[n];
            acc0 *= s;
            acc1 *= s;
        }
        unsigned pack = f2bf(acc0) | (f2bf(acc1) << 16);
        *(unsigned int*)&smem[(size_t)lrow * ROWSTRIDE + lane * 2] = pack;
    }
    __syncthreads();

    // MFMA (R6-verified layout: A m=lane&15 k=quad*8+i; B row-major W bf16;
    // C/D col=lane&15 row=quad*4+reg). Wave: rows (wv&1)*16, cols (wv>>1)*64.
    {
        int quad = lane >> 4, m16 = lane & 15;
        int lrow = (wv & 1) * 16 + m16;
        v8s afrag[4];
#pragma unroll
        for (int kk = 0; kk < 4; ++kk)
            afrag[kk] = *(const v8s*)&smem[lrow * ROWSTRIDE + kk * 32 + quad * 8];
        int rbase = nb0 + (wv & 1) * 16 + quad * 4;
        int jbase = (wv >> 1) * 64;
#pragma unroll
        for (int jt = 0; jt < 4; ++jt) {
            int jcol = jbase + jt * 16 + m16;
            v4f acc = {0.f, 0.f, 0.f, 0.f};
#pragma unroll
            for (int kk = 0; kk < 4; ++kk) {
                v8s bfrag = Wb8[jcol * 16 + kk * 4 + quad];
                acc = __builtin_amdgcn_mfma_f32_16x16x32_bf16(afrag[kk], bfrag,
                                                              acc, 0, 0, 0);
            }
            float bj = bias[jcol];
#pragma unroll
            for (int r = 0; r < 4; ++r) {
                int row = rbase + r;
                if (row < N) out[(size_t)row * 128 + jcol] = acc[r] + bj;
            }
        }
    }
}

extern "C" void kernel_launch(void* const* d_in, const int* in_sizes, int n_in,
                              void* d_out, int out_size, void* d_ws, size_t ws_size,
                              hipStream_t stream) {
    const float* x = (const float*)d_in[0];
    const int* idx = (const int*)d_in[1];
    const float* W = (const float*)d_in[2];
    const float* b = (const float*)d_in[3];
    float* out = (float*)d_out;

    const int N = in_sizes[0] / 128;     // 50000
    const int E = in_sizes[1] / 2;       // 800000
    const int nrb = (N + 255) / 256;     // 196 row-blocks (nrb*256 > N: pad row ok)

    char* p = (char*)d_ws;
    auto alloc = [&](size_t bytes) {
        char* r = p;
        p += (bytes + 63) & ~(size_t)63;
        return r;
    };
    int* cnt = (int*)alloc((size_t)N * CSTRIDE * 4);                       // 3.2 MB
    unsigned short* ell = (unsigned short*)alloc((size_t)N * ELLCAP * 2);  // 6.4 MB
    float* dis = (float*)alloc((size_t)N * 4);
    unsigned char* degc = (unsigned char*)alloc((size_t)N);
    unsigned int* xs = (unsigned int*)alloc((size_t)nrb * 256 * 128 * 2);  // 12.85 MB
    ushort4* wb = (ushort4*)alloc(128 * 128 * 2);                          // 32 KB

    hipMemsetAsync(cnt, 0, (size_t)N * CSTRIDE * sizeof(int), stream);

    k_fill<<<(E / 4 + 255) / 256, 256, 0, stream>>>(idx, cnt, ell, E);
    k_prep<<<nrb + 16, 256, 0, stream>>>(cnt, (const float2*)x, (const float4*)W,
                                         dis, degc, xs, wb, N, nrb);
    k_fused<<<(N + 31) / 32, 256, 0, stream>>>(ell, degc, dis, xs, (const v8s*)wb,
                                               b, out, N);
}

// Round 10
// 148.907 us; speedup vs baseline: 2.0669x; 1.3994x over previous
//
#include <hip/hip_runtime.h>
#include <hip/hip_bf16.h>

// GCN layer: out = (D^-1/2 A D^-1/2 X) W^T + b
// Round 10: replace the atomic ELL build (hard ~50us fabric-atomic floor,
// R5/R9 evidence) with two-pass LDS-histogram binning:
//   A: bin edges by row>>8 (196 bins). LDS hist + ONE global atomic per
//      bin per block (77K total vs 800K), scatter packed (local,col) pairs.
//      W-cast interleaved.
//   B: one block per bin: build ELL in LDS (LDS atomics only), coalesced
//      32KB dump, true-degree dis/degc, xs = bf16(dis*x) from f32 x (single
//      rounding) + zero pad row N.
//   fused: R9-verified weight-free gather (pads -> zero row) + bf16 MFMA.
//
// ws: gbin | ell[N'*64 u16] 6.4MB | pairs[196*4608 u32] 3.6MB | dis | degc |
//     xs[N'*128 bf16] 12.85MB | wb 32KB  ~= 23.2 MB (< 26 MB proven)

typedef short v8s __attribute__((ext_vector_type(8)));
typedef float v4f __attribute__((ext_vector_type(4)));

#define ELLCAP 64      // deg ~ Poisson(16); P(deg>64) ~ 1e-19/node. Guarded.
#define BINCAP 4608    // bin ~ Poisson(4082); cap at +8 sigma. Guarded.
#define ROWSTRIDE 136  // 128 bf16 + 8 pad shorts; 272 B rows (16B-aligned)

static __device__ __forceinline__ unsigned int f2bf(float f) {
    __hip_bfloat16 h = __float2bfloat16(f);  // RNE
    return (unsigned int)__builtin_bit_cast(unsigned short, h);
}

// Pass A: bin edges by row>>8. Blocks [0,16) cast W; the rest bin 2048
// edges each via LDS histogram + per-bin global reservation + scatter.
__global__ __launch_bounds__(256) void k_binA(
    const int* __restrict__ idx, int* __restrict__ gbin,
    unsigned int* __restrict__ pairs, const float4* __restrict__ w4,
    ushort4* __restrict__ wb4, int E, int nbins) {
    int b = blockIdx.x;
    const int t = threadIdx.x;
    if (b < 16) {  // W cast: 16 blocks x 256 thr = 4096 float4s
        int i = b * 256 + t;
        float4 v = w4[i];
        ushort4 o;
        o.x = (unsigned short)f2bf(v.x);
        o.y = (unsigned short)f2bf(v.y);
        o.z = (unsigned short)f2bf(v.z);
        o.w = (unsigned short)f2bf(v.w);
        wb4[i] = o;
        return;
    }
    b -= 16;
    __shared__ int hist[256];
    __shared__ int base[256];
    hist[t] = 0;
    __syncthreads();

    int e0 = b * 2048 + t * 8;
    int nv = E - e0;
    nv = nv > 8 ? 8 : (nv < 0 ? 0 : nv);
    int rows[8], cols[8];
    if (nv == 8) {
        int4 a0 = *(const int4*)&idx[e0];
        int4 a1 = *(const int4*)&idx[e0 + 4];
        int4 c0 = *(const int4*)&idx[E + e0];
        int4 c1 = *(const int4*)&idx[E + e0 + 4];
        rows[0] = a0.x; rows[1] = a0.y; rows[2] = a0.z; rows[3] = a0.w;
        rows[4] = a1.x; rows[5] = a1.y; rows[6] = a1.z; rows[7] = a1.w;
        cols[0] = c0.x; cols[1] = c0.y; cols[2] = c0.z; cols[3] = c0.w;
        cols[4] = c1.x; cols[5] = c1.y; cols[6] = c1.z; cols[7] = c1.w;
    } else {
        for (int k = 0; k < 8; ++k) {
            rows[k] = (k < nv) ? idx[e0 + k] : 0;
            cols[k] = (k < nv) ? idx[E + e0 + k] : 0;
        }
    }
#pragma unroll
    for (int k = 0; k < 8; ++k)
        if (k < nv) atomicAdd(&hist[rows[k] >> 8], 1);
    __syncthreads();
    if (t < nbins) base[t] = atomicAdd(&gbin[t], hist[t]);  // 196/block, 3 waves
    __syncthreads();
    hist[t] = 0;
    __syncthreads();
#pragma unroll
    for (int k = 0; k < 8; ++k) {
        if (k < nv) {
            int bin = rows[k] >> 8;
            int pos = base[bin] + atomicAdd(&hist[bin], 1);
            if (pos < BINCAP)
                pairs[(size_t)bin * BINCAP + pos] =
                    (unsigned)(((rows[k] & 255) << 16) | cols[k]);
        }
    }
}

// Pass B: one block per bin (256 rows). Build ELL in LDS (LDS atomics),
// coalesced dump; true-degree dis/degc; xs = bf16(dis[r]*x[r]) from f32 x
// (rows >= N, incl. pad row N, written as zeros).
__global__ __launch_bounds__(1024) void k_binB(
    const unsigned int* __restrict__ pairs, const int* __restrict__ gbin,
    unsigned short* __restrict__ ell, unsigned char* __restrict__ degc,
    float* __restrict__ dis, const float2* __restrict__ x2,
    unsigned int* __restrict__ xs32, int N) {
    __shared__ __align__(16) unsigned short lell[256 * ELLCAP];  // 32 KB
    __shared__ int cnt_l[256];
    __shared__ float sdis[256];
    const int bin = blockIdx.x;
    const int t = threadIdx.x;
    if (t < 256) cnt_l[t] = 0;
    __syncthreads();

    int m = gbin[bin];
    if (m > BINCAP) m = BINCAP;
    for (int i = t; i < m; i += 1024) {
        unsigned pv = pairs[(size_t)bin * BINCAP + i];
        int local = pv >> 16;
        int slot = atomicAdd(&cnt_l[local], 1);  // LDS atomic; true count
        if (slot < ELLCAP) lell[local * ELLCAP + slot] = (unsigned short)(pv & 0xFFFF);
    }
    __syncthreads();

    if (t < 256) {
        int r = bin * 256 + t;
        float s = 0.f;
        if (r < N) {
            int d = cnt_l[t];
            s = (d > 0) ? rsqrtf((float)d) : 0.0f;  // TRUE degree for norm
            dis[r] = s;
            degc[r] = (unsigned char)(d > ELLCAP ? ELLCAP : d);
        }
        sdis[t] = s;
    }
    __syncthreads();

    // coalesced ELL dump: 32 KB = 8192 dwords (garbage slots never read)
    {
        unsigned int* gell = (unsigned int*)(ell + (size_t)bin * 256 * ELLCAP);
        const unsigned int* sell = (const unsigned int*)lell;
        for (int i = t; i < 8192; i += 1024) gell[i] = sell[i];
    }

    // xs scaling: 256 rows x 64 float2 reads (guarded), bf16x2 packed writes
    size_t xbase = (size_t)bin * 16384;
    for (int i = t; i < 16384; i += 1024) {
        int lr = i >> 6;
        unsigned ov = 0u;
        if (bin * 256 + lr < N) {
            float2 v = x2[xbase + i];
            float ss = sdis[lr];
            ov = f2bf(v.x * ss) | (f2bf(v.y * ss) << 16);
        }
        xs32[xbase + i] = ov;  // rows >= N (incl. pad row N) -> zeros
    }
}

// Fused gather + GEMM (R9-verified). Block = 4 waves, 32 output rows.
// Gather: one wave/node, lane owns 1 dword (2 bf16 ch). Pad slots -> row N
// (zeros). Inner loop: 16 readlanes + 16 loads in flight + 32 adds.
__global__ __launch_bounds__(256) void k_fused(
    const unsigned short* __restrict__ ell, const unsigned char* __restrict__ degc,
    const float* __restrict__ dis, const unsigned int* __restrict__ xs32,
    const v8s* __restrict__ Wb8, const float* __restrict__ bias,
    float* __restrict__ out, int N) {
    __shared__ __align__(16) unsigned short smem[32 * ROWSTRIDE];
    const int nb0 = blockIdx.x * 32;
    const int wv = threadIdx.x >> 6, lane = threadIdx.x & 63;

    for (int i = 0; i < 8; ++i) {
        int lrow = wv * 8 + i;
        int n = nb0 + lrow;
        float acc0 = 0.f, acc1 = 0.f;
        if (n < N) {
            int d = degc[n];
            int cl = ell[(size_t)n * ELLCAP + lane];  // stale slots never used
            int c = (lane < d) ? cl : N;              // pad -> zero row
            for (int j = 0; j < d; j += 16) {         // j in {0,16,32,48}
                int cc[16];
#pragma unroll
                for (int u = 0; u < 16; ++u)
                    cc[u] = __builtin_amdgcn_readlane(c, j + u);  // idx <= 63
                unsigned uu[16];
#pragma unroll
                for (int u = 0; u < 16; ++u)
                    uu[u] = xs32[(size_t)cc[u] * 64 + lane];
#pragma unroll
                for (int u = 0; u < 16; ++u) {
                    acc0 += __builtin_bit_cast(float, uu[u] << 16);
                    acc1 += __builtin_bit_cast(float, uu[u] & 0xFFFF0000u);
                }
            }
            float s = dis[n];
            acc0 *= s;
            acc1 *= s;
        }
        unsigned pack = f2bf(acc0) | (f2bf(acc1) << 16);
        *(unsigned int*)&smem[(size_t)lrow * ROWSTRIDE + lane * 2] = pack;
    }
    __syncthreads();

    // MFMA (R6-verified layout: A m=lane&15 k=quad*8+i; B row-major W bf16;
    // C/D col=lane&15 row=quad*4+reg). Wave: rows (wv&1)*16, cols (wv>>1)*64.
    {
        int quad = lane >> 4, m16 = lane & 15;
        int lrow = (wv & 1) * 16 + m16;
        v8s afrag[4];
#pragma unroll
        for (int kk = 0; kk < 4; ++kk)
            afrag[kk] = *(const v8s*)&smem[lrow * ROWSTRIDE + kk * 32 + quad * 8];
        int rbase = nb0 + (wv & 1) * 16 + quad * 4;
        int jbase = (wv >> 1) * 64;
#pragma unroll
        for (int jt = 0; jt < 4; ++jt) {
            int jcol = jbase + jt * 16 + m16;
            v4f acc = {0.f, 0.f, 0.f, 0.f};
#pragma unroll
            for (int kk = 0; kk < 4; ++kk) {
                v8s bfrag = Wb8[jcol * 16 + kk * 4 + quad];
                acc = __builtin_amdgcn_mfma_f32_16x16x32_bf16(afrag[kk], bfrag,
                                                              acc, 0, 0, 0);
            }
            float bj = bias[jcol];
#pragma unroll
            for (int r = 0; r < 4; ++r) {
                int row = rbase + r;
                if (row < N) out[(size_t)row * 128 + jcol] = acc[r] + bj;
            }
        }
    }
}

extern "C" void kernel_launch(void* const* d_in, const int* in_sizes, int n_in,
                              void* d_out, int out_size, void* d_ws, size_t ws_size,
                              hipStream_t stream) {
    const float* x = (const float*)d_in[0];
    const int* idx = (const int*)d_in[1];
    const float* W = (const float*)d_in[2];
    const float* b = (const float*)d_in[3];
    float* out = (float*)d_out;

    const int N = in_sizes[0] / 128;      // 50000
    const int E = in_sizes[1] / 2;        // 800000
    const int nbins = (N + 255) / 256;    // 196 (<= 256 required)
    const int nrows = nbins * 256;        // 50176 (covers pad row N)

    char* p = (char*)d_ws;
    auto alloc = [&](size_t bytes) {
        char* r = p;
        p += (bytes + 63) & ~(size_t)63;
        return r;
    };
    int* gbin = (int*)alloc((size_t)nbins * 4);
    unsigned short* ell = (unsigned short*)alloc((size_t)nrows * ELLCAP * 2);  // 6.4 MB
    unsigned int* pairs = (unsigned int*)alloc((size_t)nbins * BINCAP * 4);    // 3.6 MB
    float* dis = (float*)alloc((size_t)N * 4);
    unsigned char* degc = (unsigned char*)alloc((size_t)N);
    unsigned int* xs = (unsigned int*)alloc((size_t)nrows * 128 * 2);  // 12.85 MB
    ushort4* wb = (ushort4*)alloc(128 * 128 * 2);                      // 32 KB

    hipMemsetAsync(gbin, 0, (size_t)nbins * sizeof(int), stream);

    const int ablocks = 16 + (E + 2047) / 2048;  // 16 W-cast + 391 binning
    k_binA<<<ablocks, 256, 0, stream>>>(idx, gbin, pairs, (const float4*)W, wb, E,
                                        nbins);
    k_binB<<<nbins, 1024, 0, stream>>>(pairs, gbin, ell, degc, dis,
                                       (const float2*)x, xs, N);
    k_fused<<<(N + 31) / 32, 256, 0, stream>>>(ell, degc, dis, xs, (const v8s*)wb,
                                               b, out, N);
}